// Round 1
// baseline (1296.029 us; speedup 1.0000x reference)
//
#include <hip/hip_runtime.h>
#include <hip/hip_bf16.h>
#include <stdint.h>

#define BB 4
#define NN 16384
#define HDIM 1024
#define HH 8
#define MM 32
#define DD 128
#define K2HD 2048

typedef unsigned int u32;
typedef unsigned short u16;
typedef __attribute__((ext_vector_type(8))) short short8;
typedef __attribute__((ext_vector_type(4))) float f32x4;

__device__ __forceinline__ float bflo(u32 v) {
    union { u32 u; float f; } c; c.u = v << 16; return c.f;
}
__device__ __forceinline__ float bfhi(u32 v) {
    union { u32 u; float f; } c; c.u = v & 0xffff0000u; return c.f;
}
__device__ __forceinline__ float bf2f(u16 v) {
    union { u32 u; float f; } c; c.u = ((u32)v) << 16; return c.f;
}
__device__ __forceinline__ u16 f2bf(float f) {
    union { float f; u32 u; } c; c.f = f;
    u32 r = c.u + 0x7fffu + ((c.u >> 16) & 1u);
    return (u16)(r >> 16);
}

// ---------------------------------------------------------------- convert
__global__ void convert_kernel(const float* __restrict__ x, const float* __restrict__ wkv,
                               const float* __restrict__ outw,
                               u16* __restrict__ xb, u16* __restrict__ wkvb, u16* __restrict__ outwb,
                               const float* __restrict__ wtq_bias, float* __restrict__ out_misc) {
    size_t i = (size_t)blockIdx.x * blockDim.x + threadIdx.x;
    size_t stride = (size_t)gridDim.x * blockDim.x;
    const size_t nx = (size_t)BB * NN * HDIM / 4;     // uint4 groups of 4 floats
    const size_t nw = (size_t)K2HD * HDIM / 4;
    const size_t no = (size_t)HDIM * HDIM / 4;
    for (size_t j = i; j < nx; j += stride) {
        float4 v = ((const float4*)x)[j];
        ushort4 o; o.x = f2bf(v.x); o.y = f2bf(v.y); o.z = f2bf(v.z); o.w = f2bf(v.w);
        ((ushort4*)xb)[j] = o;
    }
    for (size_t j = i; j < nw; j += stride) {
        float4 v = ((const float4*)wkv)[j];
        ushort4 o; o.x = f2bf(v.x); o.y = f2bf(v.y); o.z = f2bf(v.z); o.w = f2bf(v.w);
        ((ushort4*)wkvb)[j] = o;
    }
    for (size_t j = i; j < no; j += stride) {
        float4 v = ((const float4*)outw)[j];
        ushort4 o; o.x = f2bf(v.x); o.y = f2bf(v.y); o.z = f2bf(v.z); o.w = f2bf(v.w);
        ((ushort4*)outwb)[j] = o;
    }
    if (blockIdx.x == 0) {
        if (threadIdx.x == 0) out_misc[0] = 1.0f;               // temperature
        if (threadIdx.x < HH * MM) out_misc[1 + threadIdx.x] = wtq_bias[threadIdx.x];  // bias output
    }
}

// ---------------------------------------------------------------- GEMM C = A @ B^T (+bias)
// A [Mrows x Kd] bf16 row-major, Bm [Ncols x Kd] bf16 row-major, C row-major.
// 128x128 tile, BK=32, 256 threads (4 waves, each 64x64).
template<int OUT_F32>
__global__ void gemm_bt(const u16* __restrict__ A, const u16* __restrict__ Bm,
                        const float* __restrict__ bias, void* __restrict__ Cout,
                        int Ncols, int Kd) {
    __shared__ u16 lds_a[128 * 32];
    __shared__ u16 lds_b[128 * 32];
    const int t = threadIdx.x, l = t & 63, w = t >> 6;
    const int wr = w >> 1, wc = w & 1;
    const int tm = blockIdx.x, tn = blockIdx.y;

    f32x4 acc[4][4];
    const f32x4 zero = {0.f, 0.f, 0.f, 0.f};
#pragma unroll
    for (int mi = 0; mi < 4; mi++)
#pragma unroll
        for (int ni = 0; ni < 4; ni++) acc[mi][ni] = zero;

    const int off0 = t * 16;            // byte offset within 8KB tile
    const int off1 = off0 + 4096;
    const int r0 = off0 >> 6;           // row (64B per row of 32 bf16)
    const int c0 = (off0 & 63) >> 1;    // k element offset
    const int r1 = r0 + 64;
    const u16* pa0 = A + (size_t)(tm * 128 + r0) * Kd + c0;
    const u16* pa1 = A + (size_t)(tm * 128 + r1) * Kd + c0;
    const u16* pb0 = Bm + (size_t)(tn * 128 + r0) * Kd + c0;
    const u16* pb1 = Bm + (size_t)(tn * 128 + r1) * Kd + c0;

    uint4 ra0 = *(const uint4*)pa0, ra1 = *(const uint4*)pa1;
    uint4 rb0 = *(const uint4*)pb0, rb1 = *(const uint4*)pb1;

    const int nK = Kd >> 5;
    const int kg = (l >> 4) * 8;
    const int ra = wr * 64 + (l & 15);
    const int rb = wc * 64 + (l & 15);

    for (int kt = 0; kt < nK; kt++) {
        __syncthreads();
        *(uint4*)((char*)lds_a + off0) = ra0;
        *(uint4*)((char*)lds_a + off1) = ra1;
        *(uint4*)((char*)lds_b + off0) = rb0;
        *(uint4*)((char*)lds_b + off1) = rb1;
        __syncthreads();
        if (kt + 1 < nK) {
            int ko = (kt + 1) << 5;
            ra0 = *(const uint4*)(pa0 + ko); ra1 = *(const uint4*)(pa1 + ko);
            rb0 = *(const uint4*)(pb0 + ko); rb1 = *(const uint4*)(pb1 + ko);
        }
        short8 af[4], bfr[4];
#pragma unroll
        for (int mi = 0; mi < 4; mi++) af[mi] = *(const short8*)&lds_a[(ra + mi * 16) * 32 + kg];
#pragma unroll
        for (int ni = 0; ni < 4; ni++) bfr[ni] = *(const short8*)&lds_b[(rb + ni * 16) * 32 + kg];
#pragma unroll
        for (int mi = 0; mi < 4; mi++)
#pragma unroll
            for (int ni = 0; ni < 4; ni++)
                acc[mi][ni] = __builtin_amdgcn_mfma_f32_16x16x32_bf16(af[mi], bfr[ni], acc[mi][ni], 0, 0, 0);
    }

    // epilogue
#pragma unroll
    for (int ni = 0; ni < 4; ni++) {
        const int col = tn * 128 + wc * 64 + ni * 16 + (l & 15);
        const float bv = bias[col];
#pragma unroll
        for (int mi = 0; mi < 4; mi++) {
            const int row0 = tm * 128 + wr * 64 + mi * 16 + ((l >> 4) << 2);
#pragma unroll
            for (int q = 0; q < 4; q++) {
                float v = acc[mi][ni][q] + bv;
                if (OUT_F32) ((float*)Cout)[(size_t)(row0 + q) * Ncols + col] = v;
                else         ((u16*)Cout)[(size_t)(row0 + q) * Ncols + col] = f2bf(v);
            }
        }
    }
}

// ---------------------------------------------------------------- fused slice pass
// Per block: one (b,h), one chunk of 256 tokens. Computes slice scores, softmax over m,
// writes slice_weights (fp32 out), accumulates partial sum_n w[m,n]*xv[n,d] and sum_n w.
__global__ __launch_bounds__(256) void slice_pass(
        const u16* __restrict__ kv, const float* __restrict__ wtq,
        float* __restrict__ sw_out, float* __restrict__ pst, float* __restrict__ pnorm) {
    __shared__ u16 wtq_lds[MM * DD];        // [32][128] bf16, 8 KB
    __shared__ u16 w_lds[MM * 258];         // [32][258] bf16, 16.5 KB (pitch 258 -> conflict-free m-column reads)
    __shared__ u16 xv_lds[128 * 136];       // [128][136] bf16, 34 KB (272B rows: 16B-aligned)
    const int t = threadIdx.x;
    const int bh = blockIdx.y, b = bh >> 3, h = bh & 7;
    const int n0 = blockIdx.x * 256;

    for (int i = t; i < MM * DD; i += 256) wtq_lds[i] = f2bf(wtq[(size_t)h * MM * DD + i]);
    __syncthreads();

    // ---- phase 1: scores for token n = n0 + t
    const u16* xkp = kv + (size_t)(b * NN + n0 + t) * K2HD + h * DD;
    float sc[MM];
#pragma unroll
    for (int m = 0; m < MM; m++) sc[m] = 0.f;
    for (int i = 0; i < 16; i++) {          // 16 x uint4 = 128 bf16 of xk
        uint4 xv4 = ((const uint4*)xkp)[i];
        float x0 = bflo(xv4.x), x1 = bfhi(xv4.x), x2 = bflo(xv4.y), x3 = bfhi(xv4.y);
        float x4 = bflo(xv4.z), x5 = bfhi(xv4.z), x6 = bflo(xv4.w), x7 = bfhi(xv4.w);
        const u32* wq = (const u32*)wtq_lds + i * 4;
#pragma unroll
        for (int m = 0; m < MM; m++) {
            u32 w0 = wq[m * 64 + 0], w1 = wq[m * 64 + 1], w2 = wq[m * 64 + 2], w3 = wq[m * 64 + 3];
            sc[m] += x0 * bflo(w0) + x1 * bfhi(w0) + x2 * bflo(w1) + x3 * bfhi(w1)
                   + x4 * bflo(w2) + x5 * bfhi(w2) + x6 * bflo(w3) + x7 * bfhi(w3);
        }
    }
    // softmax over m (in-thread)
    float mx = sc[0];
#pragma unroll
    for (int m = 1; m < MM; m++) mx = fmaxf(mx, sc[m]);
    float ssum = 0.f;
#pragma unroll
    for (int m = 0; m < MM; m++) { sc[m] = __expf(sc[m] - mx); ssum += sc[m]; }
    float inv = 1.f / ssum;
#pragma unroll
    for (int m = 0; m < MM; m++) {
        float wv = sc[m] * inv;
        sw_out[((size_t)bh * MM + m) * NN + n0 + t] = wv;
        w_lds[m * 258 + t] = f2bf(wv);
    }

    // ---- phase 2: partial slice_token. thread -> (m = t>>3, d-range (t&7)*16)
    const int am = t >> 3;
    const int ad = (t & 7) * 16;
    float accv[16];
#pragma unroll
    for (int j = 0; j < 16; j++) accv[j] = 0.f;
    float wsum = 0.f;

    for (int half = 0; half < 2; half++) {
        __syncthreads();    // w_lds ready (1st) / xv reads of prev half done (2nd)
        {
            const int row = t >> 1;
            const int eo = (t & 1) * 64;    // element offset (64 bf16 = 8 uint4)
            const u16* src = kv + (size_t)(b * NN + n0 + half * 128 + row) * K2HD + HDIM + h * DD + eo;
            u16* dstl = &xv_lds[row * 136 + eo];
#pragma unroll
            for (int i = 0; i < 8; i++) ((uint4*)dstl)[i] = ((const uint4*)src)[i];
        }
        __syncthreads();
        for (int n = 0; n < 128; n++) {
            float wv = bf2f(w_lds[am * 258 + half * 128 + n]);
            wsum += wv;
            const u32* xvr = (const u32*)&xv_lds[n * 136 + ad];
#pragma unroll
            for (int j = 0; j < 8; j++) {
                u32 xd = xvr[j];
                accv[2 * j]     += wv * bflo(xd);
                accv[2 * j + 1] += wv * bfhi(xd);
            }
        }
    }

    float* dst = &pst[(((size_t)bh * 64 + blockIdx.x) * MM + am) * DD + ad];
#pragma unroll
    for (int j = 0; j < 16; j += 4) {
        float4 v = make_float4(accv[j], accv[j + 1], accv[j + 2], accv[j + 3]);
        *(float4*)&dst[j] = v;
    }
    if ((t & 7) == 0) pnorm[((size_t)bh * 64 + blockIdx.x) * MM + am] = wsum;
}

// ---------------------------------------------------------------- finalize (per b,h)
__global__ void finalize_kernel(const float* __restrict__ pst, const float* __restrict__ pnorm,
                                const float* __restrict__ qkvp, float* __restrict__ attn_out,
                                float* __restrict__ otw) {
    __shared__ float qt[MM * 384];      // 48 KB
    __shared__ u16 st_lds[MM * DD];     // 8 KB
    __shared__ float dots[MM * MM];     // 4 KB
    __shared__ float norm_lds[MM];
    const int bh = blockIdx.x, h = bh & 7, t = threadIdx.x;

    if (t < MM) {
        float s = 0.f;
        for (int g = 0; g < 64; g++) s += pnorm[((size_t)bh * 64 + g) * MM + t];
        norm_lds[t] = s + 1e-5f;
    }
    __syncthreads();
#pragma unroll
    for (int i = 0; i < 16; i++) {
        int e = t + i * 256;
        float s = 0.f;
        for (int g = 0; g < 64; g++) s += pst[((size_t)bh * 64 + g) * 4096 + e];
        st_lds[e] = f2bf(s / norm_lds[e >> 7]);
    }
    __syncthreads();
    const float* qw = qkvp + (size_t)h * DD * 384;
    for (int i = 0; i < 48; i++) {
        int j = t + i * 256;
        int m = j / 384, e = j - m * 384;
        float s = 0.f;
        for (int d = 0; d < DD; d++) s += bf2f(st_lds[m * DD + d]) * qw[d * 384 + e];
        qt[m * 384 + e] = s;
    }
    __syncthreads();
    const float scale = 0.08838834764831845f;
#pragma unroll
    for (int i = 0; i < 4; i++) {
        int idx = t * 4 + i;
        int qi = idx >> 5, kj = idx & 31;
        float s = 0.f;
        for (int d = 0; d < DD; d++) s += qt[qi * 384 + d] * qt[kj * 384 + 128 + d];
        dots[idx] = s * scale;
    }
    __syncthreads();
    if (t < MM) {
        float mx = -1e30f;
        float ex[MM];
#pragma unroll
        for (int j = 0; j < MM; j++) mx = fmaxf(mx, dots[t * MM + j]);
        float sm = 0.f;
#pragma unroll
        for (int j = 0; j < MM; j++) { ex[j] = __expf(dots[t * MM + j] - mx); sm += ex[j]; }
        float inv = 1.f / sm;
#pragma unroll
        for (int j = 0; j < MM; j++) {
            float v = ex[j] * inv;
            dots[t * MM + j] = v;
            attn_out[((size_t)bh * MM + t) * MM + j] = v;
        }
    }
    __syncthreads();
#pragma unroll
    for (int i = 0; i < 16; i++) {
        int e = t + i * 256;
        int m = e >> 7, d = e & 127;
        float s = 0.f;
#pragma unroll
        for (int j = 0; j < MM; j++) s += dots[m * MM + j] * qt[j * 384 + 256 + d];
        otw[(size_t)bh * 4096 + e] = s;
    }
}

// ---------------------------------------------------------------- scatter y[n, h*128+d] = sum_m ot[m,d]*w[m,n]
__global__ void scatter_kernel(const float* __restrict__ otw, const float* __restrict__ sw,
                               u16* __restrict__ y) {
    __shared__ float ot_lds[MM * 132];  // phys: m*132 + (d>>5)*33 + (d&31)  (conflict-free dq groups)
    __shared__ float w_lds[MM * 64];
    const int bh = blockIdx.y, b = bh >> 3, h = bh & 7, t = threadIdx.x;
    const int n0 = blockIdx.x * 64;

    for (int i = t; i < MM * DD; i += 256) {
        int m = i >> 7, d = i & 127;
        ot_lds[m * 132 + (d >> 5) * 33 + (d & 31)] = otw[(size_t)bh * 4096 + i];
    }
    for (int i = t; i < MM * 64; i += 256) {
        int m = i >> 6, nl = i & 63;
        w_lds[i] = sw[((size_t)bh * MM + m) * NN + n0 + nl];
    }
    __syncthreads();

    const int nl = t >> 2, dq = t & 3;
    float acc[32];
#pragma unroll
    for (int j = 0; j < 32; j++) acc[j] = 0.f;
    for (int m = 0; m < MM; m++) {
        float wv = w_lds[m * 64 + nl];
        const float* otr = &ot_lds[m * 132 + dq * 33];
#pragma unroll
        for (int j = 0; j < 32; j++) acc[j] += wv * otr[j];
    }
    u16* dstp = y + (size_t)(b * NN + n0 + nl) * HDIM + h * DD + dq * 32;
#pragma unroll
    for (int j = 0; j < 16; j++) {
        u32 pk = (u32)f2bf(acc[2 * j]) | ((u32)f2bf(acc[2 * j + 1]) << 16);
        ((u32*)dstp)[j] = pk;
    }
}

// ---------------------------------------------------------------- launch
extern "C" void kernel_launch(void* const* d_in, const int* in_sizes, int n_in,
                              void* d_out, int out_size, void* d_ws, size_t ws_size,
                              hipStream_t stream) {
    const float* x        = (const float*)d_in[0];
    const float* wkv      = (const float*)d_in[1];
    const float* bkv      = (const float*)d_in[2];
    const float* wtq      = (const float*)d_in[3];
    const float* wtq_bias = (const float*)d_in[4];
    const float* qkvp     = (const float*)d_in[5];
    const float* outw     = (const float*)d_in[6];
    const float* outb     = (const float*)d_in[7];

    float* out  = (float*)d_out;
    float* out0 = out;                      // [B,N,HD]           67108864
    float* out1 = out + 67108864;           // slice_weights      16777216
    float* out2 = out + 83886080;           // temperature        1
    // out3 = out2 + 1 (bias, 256)  -- written by convert via out2 base
    float* out4 = out + 83886337;           // attn_weights       32768

    char* ws = (char*)d_ws;
    u16*   xb    = (u16*)(ws);                          // 134217728 B (reused as y after GEMM1)
    u16*   kvb   = (u16*)(ws + 134217728);              // 268435456 B
    u16*   wkvb  = (u16*)(ws + 402653184);              // 4194304 B
    u16*   outwb = (u16*)(ws + 406847488);              // 2097152 B
    float* pst   = (float*)(ws + 408944640);            // 33554432 B
    float* pnorm = (float*)(ws + 442499072);            // 262144 B
    float* otws  = (float*)(ws + 442761216);            // 524288 B

    convert_kernel<<<dim3(2048), dim3(256), 0, stream>>>(x, wkv, outw, xb, wkvb, outwb, wtq_bias, out2);
    gemm_bt<0><<<dim3(512, 16), dim3(256), 0, stream>>>(xb, wkvb, bkv, (void*)kvb, K2HD, HDIM);
    slice_pass<<<dim3(64, 32), dim3(256), 0, stream>>>(kvb, wtq, out1, pst, pnorm);
    finalize_kernel<<<dim3(32), dim3(256), 0, stream>>>(pst, pnorm, qkvp, out4, otws);
    scatter_kernel<<<dim3(256, 32), dim3(256), 0, stream>>>(otws, out1, xb);
    gemm_bt<1><<<dim3(512, 8), dim3(256), 0, stream>>>(xb, outwb, outb, (void*)out0, HDIM, HDIM);
}

// Round 2
// 1257.457 us; speedup vs baseline: 1.0307x; 1.0307x over previous
//
#include <hip/hip_runtime.h>
#include <hip/hip_bf16.h>
#include <stdint.h>

#define BB 4
#define NN 16384
#define HDIM 1024
#define HH 8
#define MM 32
#define DD 128
#define K2HD 2048

typedef unsigned int u32;
typedef unsigned short u16;
typedef __attribute__((ext_vector_type(8))) short short8;
typedef __attribute__((ext_vector_type(4))) float f32x4;

__device__ __forceinline__ float bflo(u32 v) {
    union { u32 u; float f; } c; c.u = v << 16; return c.f;
}
__device__ __forceinline__ float bfhi(u32 v) {
    union { u32 u; float f; } c; c.u = v & 0xffff0000u; return c.f;
}
__device__ __forceinline__ float bf2f(u16 v) {
    union { u32 u; float f; } c; c.u = ((u32)v) << 16; return c.f;
}
__device__ __forceinline__ u16 f2bf(float f) {
    union { float f; u32 u; } c; c.f = f;
    u32 r = c.u + 0x7fffu + ((c.u >> 16) & 1u);
    return (u16)(r >> 16);
}

__device__ __forceinline__ void gload16(const u16* g, u16* l) {
    __builtin_amdgcn_global_load_lds(
        (const __attribute__((address_space(1))) void*)g,
        (__attribute__((address_space(3))) void*)l, 16, 0, 0);
}

// ---------------------------------------------------------------- convert
__global__ void convert_kernel(const float* __restrict__ x, const float* __restrict__ wkv,
                               const float* __restrict__ outw,
                               u16* __restrict__ xb, u16* __restrict__ wkvb, u16* __restrict__ outwb,
                               const float* __restrict__ wtq_bias, float* __restrict__ out_misc) {
    size_t i = (size_t)blockIdx.x * blockDim.x + threadIdx.x;
    size_t stride = (size_t)gridDim.x * blockDim.x;
    const size_t nx = (size_t)BB * NN * HDIM / 4;     // uint4 groups of 4 floats
    const size_t nw = (size_t)K2HD * HDIM / 4;
    const size_t no = (size_t)HDIM * HDIM / 4;
    for (size_t j = i; j < nx; j += stride) {
        float4 v = ((const float4*)x)[j];
        ushort4 o; o.x = f2bf(v.x); o.y = f2bf(v.y); o.z = f2bf(v.z); o.w = f2bf(v.w);
        ((ushort4*)xb)[j] = o;
    }
    for (size_t j = i; j < nw; j += stride) {
        float4 v = ((const float4*)wkv)[j];
        ushort4 o; o.x = f2bf(v.x); o.y = f2bf(v.y); o.z = f2bf(v.z); o.w = f2bf(v.w);
        ((ushort4*)wkvb)[j] = o;
    }
    for (size_t j = i; j < no; j += stride) {
        float4 v = ((const float4*)outw)[j];
        ushort4 o; o.x = f2bf(v.x); o.y = f2bf(v.y); o.z = f2bf(v.z); o.w = f2bf(v.w);
        ((ushort4*)outwb)[j] = o;
    }
    if (blockIdx.x == 0) {
        if (threadIdx.x == 0) out_misc[0] = 1.0f;               // temperature
        if (threadIdx.x < HH * MM) out_misc[1 + threadIdx.x] = wtq_bias[threadIdx.x];  // bias output
    }
}

// ---------------------------------------------------------------- GEMM C = A @ B^T (+bias)
// m97 structure: 128x128 tile, BK=32, 4 waves, global_load_lds width=16,
// 2-barrier K-loop, XCD-aware swizzled 1D grid.
template<int OUT_F32>
__global__ __launch_bounds__(256) void gemm_bt_v2(
        const u16* __restrict__ A, const u16* __restrict__ Bm,
        const float* __restrict__ bias, void* __restrict__ Cout,
        int Ncols, int Kd, int ntn) {
    __shared__ u16 lds_a[128 * 32];
    __shared__ u16 lds_b[128 * 32];
    const int t = threadIdx.x, l = t & 63, w = t >> 6;
    const int wr = w >> 1, wc = w & 1;

    // XCD-aware bijective swizzle (nwg % 8 == 0 for both gemms)
    const int nwg = gridDim.x;
    const int cpx = nwg >> 3;
    const int bid = blockIdx.x;
    const int swz = (bid & 7) * cpx + (bid >> 3);
    const int tm = swz / ntn, tn = swz % ntn;

    f32x4 acc[4][4];
    const f32x4 zero = {0.f, 0.f, 0.f, 0.f};
#pragma unroll
    for (int mi = 0; mi < 4; mi++)
#pragma unroll
        for (int ni = 0; ni < 4; ni++) acc[mi][ni] = zero;

    // staging addresses: wave w inst j covers rows w*32+j*16+(l>>2), k (l&3)*8
    const int srow = w * 32 + (l >> 2);
    const int scol = (l & 3) * 8;
    const u16* ga = A + (size_t)(tm * 128 + srow) * Kd + scol;
    const u16* gb = Bm + (size_t)(tn * 128 + srow) * Kd + scol;
    u16* la = &lds_a[(w * 32) * 32];      // wave-uniform LDS bases
    u16* lb = &lds_b[(w * 32) * 32];
    const size_t rstep = (size_t)16 * Kd; // +16 rows

    const int nK = Kd >> 5;
    const int kg = (l >> 4) * 8;
    const int ra = wr * 64 + (l & 15);
    const int rb = wc * 64 + (l & 15);

    for (int kt = 0; kt < nK; kt++) {
        __syncthreads();                   // LDS readers of tile kt-1 done
        const int ko = kt << 5;
        gload16(ga + ko,         la);
        gload16(ga + ko + rstep, la + 16 * 32);
        gload16(gb + ko,         lb);
        gload16(gb + ko + rstep, lb + 16 * 32);
        __syncthreads();                   // drains vmcnt(0): tile kt in LDS

        short8 af[4], bfr[4];
#pragma unroll
        for (int mi = 0; mi < 4; mi++) af[mi] = *(const short8*)&lds_a[(ra + mi * 16) * 32 + kg];
#pragma unroll
        for (int ni = 0; ni < 4; ni++) bfr[ni] = *(const short8*)&lds_b[(rb + ni * 16) * 32 + kg];
#pragma unroll
        for (int mi = 0; mi < 4; mi++)
#pragma unroll
            for (int ni = 0; ni < 4; ni++)
                acc[mi][ni] = __builtin_amdgcn_mfma_f32_16x16x32_bf16(af[mi], bfr[ni], acc[mi][ni], 0, 0, 0);
    }

    // epilogue
#pragma unroll
    for (int ni = 0; ni < 4; ni++) {
        const int col = tn * 128 + wc * 64 + ni * 16 + (l & 15);
        const float bv = bias[col];
#pragma unroll
        for (int mi = 0; mi < 4; mi++) {
            const int row0 = tm * 128 + wr * 64 + mi * 16 + ((l >> 4) << 2);
#pragma unroll
            for (int q = 0; q < 4; q++) {
                float v = acc[mi][ni][q] + bv;
                if (OUT_F32) ((float*)Cout)[(size_t)(row0 + q) * Ncols + col] = v;
                else         ((u16*)Cout)[(size_t)(row0 + q) * Ncols + col] = f2bf(v);
            }
        }
    }
}

// ---------------------------------------------------------------- fused slice pass
// Per block: one (b,h), one chunk of 256 tokens. Computes slice scores, softmax over m,
// writes slice_weights (fp32 out), accumulates partial sum_n w[m,n]*xv[n,d] and sum_n w.
__global__ __launch_bounds__(256) void slice_pass(
        const u16* __restrict__ kv, const float* __restrict__ wtq,
        float* __restrict__ sw_out, float* __restrict__ pst, float* __restrict__ pnorm) {
    __shared__ u16 wtq_lds[MM * DD];        // [32][128] bf16, 8 KB
    __shared__ u16 w_lds[MM * 258];         // [32][258] bf16, 16.5 KB (pitch 258 -> conflict-free m-column reads)
    __shared__ u16 xv_lds[128 * 136];       // [128][136] bf16, 34 KB (272B rows: 16B-aligned)
    const int t = threadIdx.x;
    const int bh = blockIdx.y, b = bh >> 3, h = bh & 7;
    const int n0 = blockIdx.x * 256;

    for (int i = t; i < MM * DD; i += 256) wtq_lds[i] = f2bf(wtq[(size_t)h * MM * DD + i]);
    __syncthreads();

    // ---- phase 1: scores for token n = n0 + t
    const u16* xkp = kv + (size_t)(b * NN + n0 + t) * K2HD + h * DD;
    float sc[MM];
#pragma unroll
    for (int m = 0; m < MM; m++) sc[m] = 0.f;
    for (int i = 0; i < 16; i++) {          // 16 x uint4 = 128 bf16 of xk
        uint4 xv4 = ((const uint4*)xkp)[i];
        float x0 = bflo(xv4.x), x1 = bfhi(xv4.x), x2 = bflo(xv4.y), x3 = bfhi(xv4.y);
        float x4 = bflo(xv4.z), x5 = bfhi(xv4.z), x6 = bflo(xv4.w), x7 = bfhi(xv4.w);
        const u32* wq = (const u32*)wtq_lds + i * 4;
#pragma unroll
        for (int m = 0; m < MM; m++) {
            u32 w0 = wq[m * 64 + 0], w1 = wq[m * 64 + 1], w2 = wq[m * 64 + 2], w3 = wq[m * 64 + 3];
            sc[m] += x0 * bflo(w0) + x1 * bfhi(w0) + x2 * bflo(w1) + x3 * bfhi(w1)
                   + x4 * bflo(w2) + x5 * bfhi(w2) + x6 * bflo(w3) + x7 * bfhi(w3);
        }
    }
    // softmax over m (in-thread)
    float mx = sc[0];
#pragma unroll
    for (int m = 1; m < MM; m++) mx = fmaxf(mx, sc[m]);
    float ssum = 0.f;
#pragma unroll
    for (int m = 0; m < MM; m++) { sc[m] = __expf(sc[m] - mx); ssum += sc[m]; }
    float inv = 1.f / ssum;
#pragma unroll
    for (int m = 0; m < MM; m++) {
        float wv = sc[m] * inv;
        sw_out[((size_t)bh * MM + m) * NN + n0 + t] = wv;
        w_lds[m * 258 + t] = f2bf(wv);
    }

    // ---- phase 2: partial slice_token. thread -> (m = t>>3, d-range (t&7)*16)
    const int am = t >> 3;
    const int ad = (t & 7) * 16;
    float accv[16];
#pragma unroll
    for (int j = 0; j < 16; j++) accv[j] = 0.f;
    float wsum = 0.f;

    for (int half = 0; half < 2; half++) {
        __syncthreads();    // w_lds ready (1st) / xv reads of prev half done (2nd)
        {
            const int row = t >> 1;
            const int eo = (t & 1) * 64;    // element offset (64 bf16 = 8 uint4)
            const u16* src = kv + (size_t)(b * NN + n0 + half * 128 + row) * K2HD + HDIM + h * DD + eo;
            u16* dstl = &xv_lds[row * 136 + eo];
#pragma unroll
            for (int i = 0; i < 8; i++) ((uint4*)dstl)[i] = ((const uint4*)src)[i];
        }
        __syncthreads();
        for (int n = 0; n < 128; n++) {
            float wv = bf2f(w_lds[am * 258 + half * 128 + n]);
            wsum += wv;
            const u32* xvr = (const u32*)&xv_lds[n * 136 + ad];
#pragma unroll
            for (int j = 0; j < 8; j++) {
                u32 xd = xvr[j];
                accv[2 * j]     += wv * bflo(xd);
                accv[2 * j + 1] += wv * bfhi(xd);
            }
        }
    }

    float* dst = &pst[(((size_t)bh * 64 + blockIdx.x) * MM + am) * DD + ad];
#pragma unroll
    for (int j = 0; j < 16; j += 4) {
        float4 v = make_float4(accv[j], accv[j + 1], accv[j + 2], accv[j + 3]);
        *(float4*)&dst[j] = v;
    }
    if ((t & 7) == 0) pnorm[((size_t)bh * 64 + blockIdx.x) * MM + am] = wsum;
}

// ---------------------------------------------------------------- finalize (per b,h)
__global__ void finalize_kernel(const float* __restrict__ pst, const float* __restrict__ pnorm,
                                const float* __restrict__ qkvp, float* __restrict__ attn_out,
                                float* __restrict__ otw) {
    __shared__ float qt[MM * 384];      // 48 KB
    __shared__ u16 st_lds[MM * DD];     // 8 KB
    __shared__ float dots[MM * MM];     // 4 KB
    __shared__ float norm_lds[MM];
    const int bh = blockIdx.x, h = bh & 7, t = threadIdx.x;

    if (t < MM) {
        float s = 0.f;
        for (int g = 0; g < 64; g++) s += pnorm[((size_t)bh * 64 + g) * MM + t];
        norm_lds[t] = s + 1e-5f;
    }
    __syncthreads();
#pragma unroll
    for (int i = 0; i < 16; i++) {
        int e = t + i * 256;
        float s = 0.f;
        for (int g = 0; g < 64; g++) s += pst[((size_t)bh * 64 + g) * 4096 + e];
        st_lds[e] = f2bf(s / norm_lds[e >> 7]);
    }
    __syncthreads();
    const float* qw = qkvp + (size_t)h * DD * 384;
    for (int i = 0; i < 48; i++) {
        int j = t + i * 256;
        int m = j / 384, e = j - m * 384;
        float s = 0.f;
        for (int d = 0; d < DD; d++) s += bf2f(st_lds[m * DD + d]) * qw[d * 384 + e];
        qt[m * 384 + e] = s;
    }
    __syncthreads();
    const float scale = 0.08838834764831845f;
#pragma unroll
    for (int i = 0; i < 4; i++) {
        int idx = t * 4 + i;
        int qi = idx >> 5, kj = idx & 31;
        float s = 0.f;
        for (int d = 0; d < DD; d++) s += qt[qi * 384 + d] * qt[kj * 384 + 128 + d];
        dots[idx] = s * scale;
    }
    __syncthreads();
    if (t < MM) {
        float mx = -1e30f;
        float ex[MM];
#pragma unroll
        for (int j = 0; j < MM; j++) mx = fmaxf(mx, dots[t * MM + j]);
        float sm = 0.f;
#pragma unroll
        for (int j = 0; j < MM; j++) { ex[j] = __expf(dots[t * MM + j] - mx); sm += ex[j]; }
        float inv = 1.f / sm;
#pragma unroll
        for (int j = 0; j < MM; j++) {
            float v = ex[j] * inv;
            dots[t * MM + j] = v;
            attn_out[((size_t)bh * MM + t) * MM + j] = v;
        }
    }
    __syncthreads();
#pragma unroll
    for (int i = 0; i < 16; i++) {
        int e = t + i * 256;
        int m = e >> 7, d = e & 127;
        float s = 0.f;
#pragma unroll
        for (int j = 0; j < MM; j++) s += dots[m * MM + j] * qt[j * 384 + 256 + d];
        otw[(size_t)bh * 4096 + e] = s;
    }
}

// ---------------------------------------------------------------- scatter y[n, h*128+d] = sum_m ot[m,d]*w[m,n]
__global__ void scatter_kernel(const float* __restrict__ otw, const float* __restrict__ sw,
                               u16* __restrict__ y) {
    __shared__ float ot_lds[MM * 132];  // phys: m*132 + (d>>5)*33 + (d&31)  (conflict-free dq groups)
    __shared__ float w_lds[MM * 64];
    const int bh = blockIdx.y, b = bh >> 3, h = bh & 7, t = threadIdx.x;
    const int n0 = blockIdx.x * 64;

    for (int i = t; i < MM * DD; i += 256) {
        int m = i >> 7, d = i & 127;
        ot_lds[m * 132 + (d >> 5) * 33 + (d & 31)] = otw[(size_t)bh * 4096 + i];
    }
    for (int i = t; i < MM * 64; i += 256) {
        int m = i >> 6, nl = i & 63;
        w_lds[i] = sw[((size_t)bh * MM + m) * NN + n0 + nl];
    }
    __syncthreads();

    const int nl = t >> 2, dq = t & 3;
    float acc[32];
#pragma unroll
    for (int j = 0; j < 32; j++) acc[j] = 0.f;
    for (int m = 0; m < MM; m++) {
        float wv = w_lds[m * 64 + nl];
        const float* otr = &ot_lds[m * 132 + dq * 33];
#pragma unroll
        for (int j = 0; j < 32; j++) acc[j] += wv * otr[j];
    }
    u16* dstp = y + (size_t)(b * NN + n0 + nl) * HDIM + h * DD + dq * 32;
#pragma unroll
    for (int j = 0; j < 16; j++) {
        u32 pk = (u32)f2bf(acc[2 * j]) | ((u32)f2bf(acc[2 * j + 1]) << 16);
        ((u32*)dstp)[j] = pk;
    }
}

// ---------------------------------------------------------------- launch
extern "C" void kernel_launch(void* const* d_in, const int* in_sizes, int n_in,
                              void* d_out, int out_size, void* d_ws, size_t ws_size,
                              hipStream_t stream) {
    const float* x        = (const float*)d_in[0];
    const float* wkv      = (const float*)d_in[1];
    const float* bkv      = (const float*)d_in[2];
    const float* wtq      = (const float*)d_in[3];
    const float* wtq_bias = (const float*)d_in[4];
    const float* qkvp     = (const float*)d_in[5];
    const float* outw     = (const float*)d_in[6];
    const float* outb     = (const float*)d_in[7];

    float* out  = (float*)d_out;
    float* out0 = out;                      // [B,N,HD]           67108864
    float* out1 = out + 67108864;           // slice_weights      16777216
    float* out2 = out + 83886080;           // temperature        1
    // out3 = out2 + 1 (bias, 256)  -- written by convert via out2 base
    float* out4 = out + 83886337;           // attn_weights       32768

    char* ws = (char*)d_ws;
    u16*   xb    = (u16*)(ws);                          // 134217728 B (reused as y after GEMM1)
    u16*   kvb   = (u16*)(ws + 134217728);              // 268435456 B
    u16*   wkvb  = (u16*)(ws + 402653184);              // 4194304 B
    u16*   outwb = (u16*)(ws + 406847488);              // 2097152 B
    float* pst   = (float*)(ws + 408944640);            // 33554432 B
    float* pnorm = (float*)(ws + 442499072);            // 262144 B
    float* otws  = (float*)(ws + 442761216);            // 524288 B

    convert_kernel<<<dim3(2048), dim3(256), 0, stream>>>(x, wkv, outw, xb, wkvb, outwb, wtq_bias, out2);
    gemm_bt_v2<0><<<dim3(512 * 16), dim3(256), 0, stream>>>(xb, wkvb, bkv, (void*)kvb, K2HD, HDIM, 16);
    slice_pass<<<dim3(64, 32), dim3(256), 0, stream>>>(kvb, wtq, out1, pst, pnorm);
    finalize_kernel<<<dim3(32), dim3(256), 0, stream>>>(pst, pnorm, qkvp, out4, otws);
    scatter_kernel<<<dim3(256, 32), dim3(256), 0, stream>>>(otws, out1, xb);
    gemm_bt_v2<1><<<dim3(512 * 8), dim3(256), 0, stream>>>(xb, outwb, outb, (void*)out0, HDIM, HDIM, 8);
}

// Round 3
// 1178.265 us; speedup vs baseline: 1.0999x; 1.0672x over previous
//
#include <hip/hip_runtime.h>
#include <hip/hip_bf16.h>
#include <stdint.h>

#define BB 4
#define NN 16384
#define HDIM 1024
#define HH 8
#define MM 32
#define DD 128
#define K2HD 2048

typedef unsigned int u32;
typedef unsigned short u16;
typedef __attribute__((ext_vector_type(8))) short short8;
typedef __attribute__((ext_vector_type(4))) float f32x4;

__device__ __forceinline__ float bflo(u32 v) {
    union { u32 u; float f; } c; c.u = v << 16; return c.f;
}
__device__ __forceinline__ float bfhi(u32 v) {
    union { u32 u; float f; } c; c.u = v & 0xffff0000u; return c.f;
}
__device__ __forceinline__ float bf2f(u16 v) {
    union { u32 u; float f; } c; c.u = ((u32)v) << 16; return c.f;
}
__device__ __forceinline__ u16 f2bf(float f) {
    union { float f; u32 u; } c; c.f = f;
    u32 r = c.u + 0x7fffu + ((c.u >> 16) & 1u);
    return (u16)(r >> 16);
}

__device__ __forceinline__ void gload16(const u16* g, u16* l) {
    __builtin_amdgcn_global_load_lds(
        (const __attribute__((address_space(1))) void*)g,
        (__attribute__((address_space(3))) void*)l, 16, 0, 0);
}

// ---------------------------------------------------------------- convert
__global__ void convert_kernel(const float* __restrict__ x, const float* __restrict__ wkv,
                               const float* __restrict__ outw,
                               u16* __restrict__ xb, u16* __restrict__ wkvb, u16* __restrict__ outwb,
                               const float* __restrict__ wtq_bias, float* __restrict__ out_misc) {
    size_t i = (size_t)blockIdx.x * blockDim.x + threadIdx.x;
    size_t stride = (size_t)gridDim.x * blockDim.x;
    const size_t nx = (size_t)BB * NN * HDIM / 4;     // uint4 groups of 4 floats
    const size_t nw = (size_t)K2HD * HDIM / 4;
    const size_t no = (size_t)HDIM * HDIM / 4;
    for (size_t j = i; j < nx; j += stride) {
        float4 v = ((const float4*)x)[j];
        ushort4 o; o.x = f2bf(v.x); o.y = f2bf(v.y); o.z = f2bf(v.z); o.w = f2bf(v.w);
        ((ushort4*)xb)[j] = o;
    }
    for (size_t j = i; j < nw; j += stride) {
        float4 v = ((const float4*)wkv)[j];
        ushort4 o; o.x = f2bf(v.x); o.y = f2bf(v.y); o.z = f2bf(v.z); o.w = f2bf(v.w);
        ((ushort4*)wkvb)[j] = o;
    }
    for (size_t j = i; j < no; j += stride) {
        float4 v = ((const float4*)outw)[j];
        ushort4 o; o.x = f2bf(v.x); o.y = f2bf(v.y); o.z = f2bf(v.z); o.w = f2bf(v.w);
        ((ushort4*)outwb)[j] = o;
    }
    if (blockIdx.x == 0) {
        if (threadIdx.x == 0) out_misc[0] = 1.0f;               // temperature
        if (threadIdx.x < HH * MM) out_misc[1 + threadIdx.x] = wtq_bias[threadIdx.x];  // bias output
    }
}

// ---------------------------------------------------------------- GEMM C = A @ B^T (+bias)
// 256x256 tile, BK=32, 512 threads (8 waves 2Mx4N), 4-slot LDS ring (128 KiB),
// counted vmcnt(8) pipeline (stage kt+3 while computing kt), one raw s_barrier
// per K-tile, XOR-swizzled LDS (pre-swizzled global source + swizzled ds_read),
// setprio around MFMA clusters, XCD-aware bijective grid swizzle.
template<int OUT_F32>
__global__ __launch_bounds__(512, 2) void gemm256(
        const u16* __restrict__ A, const u16* __restrict__ Bm,
        const float* __restrict__ bias, void* __restrict__ Cout,
        int Ncols, int Kd, int ntn) {
    __shared__ u16 ldsA[4][8192];   // 4 ring slots x [256 rows][32 k] bf16 (64 KiB)
    __shared__ u16 ldsB[4][8192];   // 64 KiB
    const int t = threadIdx.x, l = t & 63, w = t >> 6;
    const int wr = w >> 2, wc = w & 3;

    const int nwg = gridDim.x;
    const int cpx = nwg >> 3;
    const int bid = blockIdx.x;
    const int swz = (bid & 7) * cpx + (bid >> 3);
    const int tm = swz / ntn, tn = swz % ntn;

    f32x4 acc[8][4];
    const f32x4 zero = {0.f, 0.f, 0.f, 0.f};
#pragma unroll
    for (int mi = 0; mi < 8; mi++)
#pragma unroll
        for (int ni = 0; ni < 4; ni++) acc[mi][ni] = zero;

    // staging: wave w, round j covers rows j*128 + w*16 + (l>>2); 16B slot (l&3).
    // pre-swizzle the global k-group so the linear gload_lds dest realizes
    // logical slot' = slot ^ ((row>>1)&3); here (row>>1)&3 == (l>>3)&3.
    const int srow = w * 16 + (l >> 2);
    const int kel  = ((l & 3) ^ ((l >> 3) & 3)) * 8;
    const u16* gA0 = A  + (size_t)(tm * 256 + srow) * Kd + kel;
    const u16* gA1 = gA0 + (size_t)128 * Kd;
    const u16* gB0 = Bm + (size_t)(tn * 256 + srow) * Kd + kel;
    const u16* gB1 = gB0 + (size_t)128 * Kd;
    const int ldst = w * 512;       // wave-uniform element offset within a half-round

    // ds_read side: frag row = (wr*128|wc*64) + f*16 + (l&15); logical k-group (l>>4);
    // physical slot = (l>>4) ^ ((row>>1)&3) = (l>>4) ^ ((l>>1)&3).
    const int arow = wr * 128 + (l & 15);
    const int brow = wc * 64 + (l & 15);
    const int koff = (((l >> 4) ^ ((l >> 1) & 3)) << 3);

    const int nK = Kd >> 5;

    // prologue: stage tiles 0,1,2 into slots 0,1,2 (4 gloads each, in order)
    {
        gload16(gA0, &ldsA[0][ldst]);           gload16(gA1, &ldsA[0][4096 + ldst]);
        gload16(gB0, &ldsB[0][ldst]);           gload16(gB1, &ldsB[0][4096 + ldst]);
        __builtin_amdgcn_sched_barrier(0);
        gload16(gA0 + 32, &ldsA[1][ldst]);      gload16(gA1 + 32, &ldsA[1][4096 + ldst]);
        gload16(gB0 + 32, &ldsB[1][ldst]);      gload16(gB1 + 32, &ldsB[1][4096 + ldst]);
        __builtin_amdgcn_sched_barrier(0);
        gload16(gA0 + 64, &ldsA[2][ldst]);      gload16(gA1 + 64, &ldsA[2][4096 + ldst]);
        gload16(gB0 + 64, &ldsB[2][ldst]);      gload16(gB1 + 64, &ldsB[2][4096 + ldst]);
    }
    asm volatile("s_waitcnt vmcnt(8)" ::: "memory");   // tile 0 landed (per wave), tiles 1,2 in flight
    __builtin_amdgcn_s_barrier();                      // cross-wave: all tile-0 stages visible

    for (int kt = 0; kt < nK; ++kt) {
        const int sk = kt & 3;
        const bool st = (kt + 3) < nK;
        const int ss = (kt + 3) & 3;
        const int ko = (kt + 3) * 32;

        // ---- phase A: A-frags + B cols 0,1; stage A-halves of tile kt+3
        short8 af[8];
#pragma unroll
        for (int mi = 0; mi < 8; mi++)
            af[mi] = *(const short8*)&ldsA[sk][(arow + mi * 16) * 32 + koff];
        short8 b0 = *(const short8*)&ldsB[sk][(brow + 0) * 32 + koff];
        short8 b1 = *(const short8*)&ldsB[sk][(brow + 16) * 32 + koff];
        if (st) {
            gload16(gA0 + ko, &ldsA[ss][ldst]);
            gload16(gA1 + ko, &ldsA[ss][4096 + ldst]);
        }
        __builtin_amdgcn_s_setprio(1);
#pragma unroll
        for (int mi = 0; mi < 8; mi++)
            acc[mi][0] = __builtin_amdgcn_mfma_f32_16x16x32_bf16(af[mi], b0, acc[mi][0], 0, 0, 0);
#pragma unroll
        for (int mi = 0; mi < 8; mi++)
            acc[mi][1] = __builtin_amdgcn_mfma_f32_16x16x32_bf16(af[mi], b1, acc[mi][1], 0, 0, 0);
        __builtin_amdgcn_s_setprio(0);

        // ---- phase B: B cols 2,3; stage B-halves of tile kt+3
        short8 b2 = *(const short8*)&ldsB[sk][(brow + 32) * 32 + koff];
        short8 b3 = *(const short8*)&ldsB[sk][(brow + 48) * 32 + koff];
        if (st) {
            gload16(gB0 + ko, &ldsB[ss][ldst]);
            gload16(gB1 + ko, &ldsB[ss][4096 + ldst]);
        }
        __builtin_amdgcn_s_setprio(1);
#pragma unroll
        for (int mi = 0; mi < 8; mi++)
            acc[mi][2] = __builtin_amdgcn_mfma_f32_16x16x32_bf16(af[mi], b2, acc[mi][2], 0, 0, 0);
#pragma unroll
        for (int mi = 0; mi < 8; mi++)
            acc[mi][3] = __builtin_amdgcn_mfma_f32_16x16x32_bf16(af[mi], b3, acc[mi][3], 0, 0, 0);
        __builtin_amdgcn_s_setprio(0);

        // ---- tile boundary: counted wait (never 0 except at tail), raw barrier
        if (kt < nK - 1) {
            if (kt <= nK - 4)      asm volatile("s_waitcnt vmcnt(8)" ::: "memory");
            else if (kt == nK - 3) asm volatile("s_waitcnt vmcnt(4)" ::: "memory");
            else                   asm volatile("s_waitcnt vmcnt(0)" ::: "memory");
            __builtin_amdgcn_s_barrier();
        }
    }

    // ---- epilogue
    const int cr = (l >> 4) * 4;
    const int cc = l & 15;
#pragma unroll
    for (int ni = 0; ni < 4; ni++) {
        const int col = tn * 256 + wc * 64 + ni * 16 + cc;
        const float bv = bias[col];
#pragma unroll
        for (int mi = 0; mi < 8; mi++) {
            const int row0 = tm * 256 + wr * 128 + mi * 16 + cr;
#pragma unroll
            for (int q = 0; q < 4; q++) {
                float v = acc[mi][ni][q] + bv;
                if (OUT_F32) ((float*)Cout)[(size_t)(row0 + q) * Ncols + col] = v;
                else         ((u16*)Cout)[(size_t)(row0 + q) * Ncols + col] = f2bf(v);
            }
        }
    }
}

// ---------------------------------------------------------------- fused slice pass
__global__ __launch_bounds__(256) void slice_pass(
        const u16* __restrict__ kv, const float* __restrict__ wtq,
        float* __restrict__ sw_out, float* __restrict__ pst, float* __restrict__ pnorm) {
    __shared__ u16 wtq_lds[MM * DD];        // [32][128] bf16, 8 KB
    __shared__ u16 w_lds[MM * 258];         // [32][258] bf16 (pitch 258 -> conflict-free m-column reads)
    __shared__ u16 xv_lds[128 * 136];       // [128][136] bf16 (272B rows: 16B-aligned)
    const int t = threadIdx.x;
    const int bh = blockIdx.y, b = bh >> 3, h = bh & 7;
    const int n0 = blockIdx.x * 256;

    for (int i = t; i < MM * DD; i += 256) wtq_lds[i] = f2bf(wtq[(size_t)h * MM * DD + i]);
    __syncthreads();

    // ---- phase 1: scores for token n = n0 + t
    const u16* xkp = kv + (size_t)(b * NN + n0 + t) * K2HD + h * DD;
    float sc[MM];
#pragma unroll
    for (int m = 0; m < MM; m++) sc[m] = 0.f;
    for (int i = 0; i < 16; i++) {          // 16 x uint4 = 128 bf16 of xk
        uint4 xv4 = ((const uint4*)xkp)[i];
        float x0 = bflo(xv4.x), x1 = bfhi(xv4.x), x2 = bflo(xv4.y), x3 = bfhi(xv4.y);
        float x4 = bflo(xv4.z), x5 = bfhi(xv4.z), x6 = bflo(xv4.w), x7 = bfhi(xv4.w);
        const u32* wq = (const u32*)wtq_lds + i * 4;
#pragma unroll
        for (int m = 0; m < MM; m++) {
            u32 w0 = wq[m * 64 + 0], w1 = wq[m * 64 + 1], w2 = wq[m * 64 + 2], w3 = wq[m * 64 + 3];
            sc[m] += x0 * bflo(w0) + x1 * bfhi(w0) + x2 * bflo(w1) + x3 * bfhi(w1)
                   + x4 * bflo(w2) + x5 * bfhi(w2) + x6 * bflo(w3) + x7 * bfhi(w3);
        }
    }
    float mx = sc[0];
#pragma unroll
    for (int m = 1; m < MM; m++) mx = fmaxf(mx, sc[m]);
    float ssum = 0.f;
#pragma unroll
    for (int m = 0; m < MM; m++) { sc[m] = __expf(sc[m] - mx); ssum += sc[m]; }
    float inv = 1.f / ssum;
#pragma unroll
    for (int m = 0; m < MM; m++) {
        float wv = sc[m] * inv;
        sw_out[((size_t)bh * MM + m) * NN + n0 + t] = wv;
        w_lds[m * 258 + t] = f2bf(wv);
    }

    // ---- phase 2: partial slice_token. thread -> (m = t>>3, d-range (t&7)*16)
    const int am = t >> 3;
    const int ad = (t & 7) * 16;
    float accv[16];
#pragma unroll
    for (int j = 0; j < 16; j++) accv[j] = 0.f;
    float wsum = 0.f;

    for (int half = 0; half < 2; half++) {
        __syncthreads();
        {
            const int row = t >> 1;
            const int eo = (t & 1) * 64;
            const u16* src = kv + (size_t)(b * NN + n0 + half * 128 + row) * K2HD + HDIM + h * DD + eo;
            u16* dstl = &xv_lds[row * 136 + eo];
#pragma unroll
            for (int i = 0; i < 8; i++) ((uint4*)dstl)[i] = ((const uint4*)src)[i];
        }
        __syncthreads();
        for (int n = 0; n < 128; n++) {
            float wv = bf2f(w_lds[am * 258 + half * 128 + n]);
            wsum += wv;
            const u32* xvr = (const u32*)&xv_lds[n * 136 + ad];
#pragma unroll
            for (int j = 0; j < 8; j++) {
                u32 xd = xvr[j];
                accv[2 * j]     += wv * bflo(xd);
                accv[2 * j + 1] += wv * bfhi(xd);
            }
        }
    }

    float* dst = &pst[(((size_t)bh * 64 + blockIdx.x) * MM + am) * DD + ad];
#pragma unroll
    for (int j = 0; j < 16; j += 4) {
        float4 v = make_float4(accv[j], accv[j + 1], accv[j + 2], accv[j + 3]);
        *(float4*)&dst[j] = v;
    }
    if ((t & 7) == 0) pnorm[((size_t)bh * 64 + blockIdx.x) * MM + am] = wsum;
}

// ---------------------------------------------------------------- finalize (per b,h)
__global__ void finalize_kernel(const float* __restrict__ pst, const float* __restrict__ pnorm,
                                const float* __restrict__ qkvp, float* __restrict__ attn_out,
                                float* __restrict__ otw) {
    __shared__ float qt[MM * 384];      // 48 KB
    __shared__ u16 st_lds[MM * DD];     // 8 KB
    __shared__ float dots[MM * MM];     // 4 KB
    __shared__ float norm_lds[MM];
    const int bh = blockIdx.x, h = bh & 7, t = threadIdx.x;

    if (t < MM) {
        float s = 0.f;
        for (int g = 0; g < 64; g++) s += pnorm[((size_t)bh * 64 + g) * MM + t];
        norm_lds[t] = s + 1e-5f;
    }
    __syncthreads();
#pragma unroll
    for (int i = 0; i < 16; i++) {
        int e = t + i * 256;
        float s = 0.f;
        for (int g = 0; g < 64; g++) s += pst[((size_t)bh * 64 + g) * 4096 + e];
        st_lds[e] = f2bf(s / norm_lds[e >> 7]);
    }
    __syncthreads();
    const float* qw = qkvp + (size_t)h * DD * 384;
    for (int i = 0; i < 48; i++) {
        int j = t + i * 256;
        int m = j / 384, e = j - m * 384;
        float s = 0.f;
        for (int d = 0; d < DD; d++) s += bf2f(st_lds[m * DD + d]) * qw[d * 384 + e];
        qt[m * 384 + e] = s;
    }
    __syncthreads();
    const float scale = 0.08838834764831845f;
#pragma unroll
    for (int i = 0; i < 4; i++) {
        int idx = t * 4 + i;
        int qi = idx >> 5, kj = idx & 31;
        float s = 0.f;
        for (int d = 0; d < DD; d++) s += qt[qi * 384 + d] * qt[kj * 384 + 128 + d];
        dots[idx] = s * scale;
    }
    __syncthreads();
    if (t < MM) {
        float mx = -1e30f;
        float ex[MM];
#pragma unroll
        for (int j = 0; j < MM; j++) mx = fmaxf(mx, dots[t * MM + j]);
        float sm = 0.f;
#pragma unroll
        for (int j = 0; j < MM; j++) { ex[j] = __expf(dots[t * MM + j] - mx); sm += ex[j]; }
        float inv = 1.f / sm;
#pragma unroll
        for (int j = 0; j < MM; j++) {
            float v = ex[j] * inv;
            dots[t * MM + j] = v;
            attn_out[((size_t)bh * MM + t) * MM + j] = v;
        }
    }
    __syncthreads();
#pragma unroll
    for (int i = 0; i < 16; i++) {
        int e = t + i * 256;
        int m = e >> 7, d = e & 127;
        float s = 0.f;
#pragma unroll
        for (int j = 0; j < MM; j++) s += dots[m * MM + j] * qt[j * 384 + 256 + d];
        otw[(size_t)bh * 4096 + e] = s;
    }
}

// ---------------------------------------------------------------- scatter y[n, h*128+d] = sum_m ot[m,d]*w[m,n]
__global__ void scatter_kernel(const float* __restrict__ otw, const float* __restrict__ sw,
                               u16* __restrict__ y) {
    __shared__ float ot_lds[MM * 132];  // phys: m*132 + (d>>5)*33 + (d&31)
    __shared__ float w_lds[MM * 64];
    const int bh = blockIdx.y, b = bh >> 3, h = bh & 7, t = threadIdx.x;
    const int n0 = blockIdx.x * 64;

    for (int i = t; i < MM * DD; i += 256) {
        int m = i >> 7, d = i & 127;
        ot_lds[m * 132 + (d >> 5) * 33 + (d & 31)] = otw[(size_t)bh * 4096 + i];
    }
    for (int i = t; i < MM * 64; i += 256) {
        int m = i >> 6, nl = i & 63;
        w_lds[i] = sw[((size_t)bh * MM + m) * NN + n0 + nl];
    }
    __syncthreads();

    const int nl = t >> 2, dq = t & 3;
    float acc[32];
#pragma unroll
    for (int j = 0; j < 32; j++) acc[j] = 0.f;
    for (int m = 0; m < MM; m++) {
        float wv = w_lds[m * 64 + nl];
        const float* otr = &ot_lds[m * 132 + dq * 33];
#pragma unroll
        for (int j = 0; j < 32; j++) acc[j] += wv * otr[j];
    }
    u16* dstp = y + (size_t)(b * NN + n0 + nl) * HDIM + h * DD + dq * 32;
#pragma unroll
    for (int j = 0; j < 16; j++) {
        u32 pk = (u32)f2bf(acc[2 * j]) | ((u32)f2bf(acc[2 * j + 1]) << 16);
        ((u32*)dstp)[j] = pk;
    }
}

// ---------------------------------------------------------------- launch
extern "C" void kernel_launch(void* const* d_in, const int* in_sizes, int n_in,
                              void* d_out, int out_size, void* d_ws, size_t ws_size,
                              hipStream_t stream) {
    const float* x        = (const float*)d_in[0];
    const float* wkv      = (const float*)d_in[1];
    const float* bkv      = (const float*)d_in[2];
    const float* wtq      = (const float*)d_in[3];
    const float* wtq_bias = (const float*)d_in[4];
    const float* qkvp     = (const float*)d_in[5];
    const float* outw     = (const float*)d_in[6];
    const float* outb     = (const float*)d_in[7];

    float* out  = (float*)d_out;
    float* out0 = out;                      // [B,N,HD]           67108864
    float* out1 = out + 67108864;           // slice_weights      16777216
    float* out2 = out + 83886080;           // temperature + bias
    float* out4 = out + 83886337;           // attn_weights       32768

    char* ws = (char*)d_ws;
    u16*   xb    = (u16*)(ws);                          // 134217728 B (reused as y after GEMM1)
    u16*   kvb   = (u16*)(ws + 134217728);              // 268435456 B
    u16*   wkvb  = (u16*)(ws + 402653184);              // 4194304 B
    u16*   outwb = (u16*)(ws + 406847488);              // 2097152 B
    float* pst   = (float*)(ws + 408944640);            // 33554432 B
    float* pnorm = (float*)(ws + 442499072);            // 262144 B
    float* otws  = (float*)(ws + 442761216);            // 524288 B

    convert_kernel<<<dim3(2048), dim3(256), 0, stream>>>(x, wkv, outw, xb, wkvb, outwb, wtq_bias, out2);
    gemm256<0><<<dim3(256 * 8), dim3(512), 0, stream>>>(xb, wkvb, bkv, (void*)kvb, K2HD, HDIM, 8);
    slice_pass<<<dim3(64, 32), dim3(256), 0, stream>>>(kvb, wtq, out1, pst, pnorm);
    finalize_kernel<<<dim3(32), dim3(256), 0, stream>>>(pst, pnorm, qkvp, out4, otws);
    scatter_kernel<<<dim3(256, 32), dim3(256), 0, stream>>>(otws, out1, xb);
    gemm256<1><<<dim3(256 * 4), dim3(512), 0, stream>>>(xb, outwb, outb, (void*)out0, HDIM, HDIM, 4);
}

// Round 4
// 1061.047 us; speedup vs baseline: 1.2215x; 1.1105x over previous
//
#include <hip/hip_runtime.h>
#include <hip/hip_bf16.h>
#include <stdint.h>

#define BB 4
#define NN 16384
#define HDIM 1024
#define HH 8
#define MM 32
#define DD 128
#define K2HD 2048

typedef unsigned int u32;
typedef unsigned short u16;
typedef __attribute__((ext_vector_type(8))) short short8;
typedef __attribute__((ext_vector_type(4))) float f32x4;

__device__ __forceinline__ float bflo(u32 v) {
    union { u32 u; float f; } c; c.u = v << 16; return c.f;
}
__device__ __forceinline__ float bfhi(u32 v) {
    union { u32 u; float f; } c; c.u = v & 0xffff0000u; return c.f;
}
__device__ __forceinline__ float bf2f(u16 v) {
    union { u32 u; float f; } c; c.u = ((u32)v) << 16; return c.f;
}
__device__ __forceinline__ u16 f2bf(float f) {
    union { float f; u32 u; } c; c.f = f;
    u32 r = c.u + 0x7fffu + ((c.u >> 16) & 1u);
    return (u16)(r >> 16);
}

__device__ __forceinline__ void gload16(const u16* g, u16* l) {
    __builtin_amdgcn_global_load_lds(
        (const __attribute__((address_space(1))) void*)g,
        (__attribute__((address_space(3))) void*)l, 16, 0, 0);
}

// ---------------------------------------------------------------- convert
__global__ void convert_kernel(const float* __restrict__ x, const float* __restrict__ wkv,
                               const float* __restrict__ outw,
                               u16* __restrict__ xb, u16* __restrict__ wkvb, u16* __restrict__ outwb,
                               const float* __restrict__ wtq_bias, float* __restrict__ out_misc) {
    size_t i = (size_t)blockIdx.x * blockDim.x + threadIdx.x;
    size_t stride = (size_t)gridDim.x * blockDim.x;
    const size_t nx = (size_t)BB * NN * HDIM / 4;     // uint4 groups of 4 floats
    const size_t nw = (size_t)K2HD * HDIM / 4;
    const size_t no = (size_t)HDIM * HDIM / 4;
    for (size_t j = i; j < nx; j += stride) {
        float4 v = ((const float4*)x)[j];
        ushort4 o; o.x = f2bf(v.x); o.y = f2bf(v.y); o.z = f2bf(v.z); o.w = f2bf(v.w);
        ((ushort4*)xb)[j] = o;
    }
    for (size_t j = i; j < nw; j += stride) {
        float4 v = ((const float4*)wkv)[j];
        ushort4 o; o.x = f2bf(v.x); o.y = f2bf(v.y); o.z = f2bf(v.z); o.w = f2bf(v.w);
        ((ushort4*)wkvb)[j] = o;
    }
    for (size_t j = i; j < no; j += stride) {
        float4 v = ((const float4*)outw)[j];
        ushort4 o; o.x = f2bf(v.x); o.y = f2bf(v.y); o.z = f2bf(v.z); o.w = f2bf(v.w);
        ((ushort4*)outwb)[j] = o;
    }
    if (blockIdx.x == 0) {
        if (threadIdx.x == 0) out_misc[0] = 1.0f;               // temperature
        if (threadIdx.x < HH * MM) out_misc[1 + threadIdx.x] = wtq_bias[threadIdx.x];  // bias output
    }
}

// ---------------------------------------------------------------- GEMM C = A @ B^T (+bias)
// 256x256 tile, BK=32, 512 threads (8 waves 2Mx4N), 4-slot LDS ring (128 KiB),
// counted vmcnt(8) pipeline, one raw s_barrier per K-tile, XOR-swizzled LDS
// (pre-swizzled global source + swizzled ds_read), setprio, XCD grid swizzle.
template<int OUT_F32>
__global__ __launch_bounds__(512, 2) void gemm256(
        const u16* __restrict__ A, const u16* __restrict__ Bm,
        const float* __restrict__ bias, void* __restrict__ Cout,
        int Ncols, int Kd, int ntn) {
    __shared__ u16 ldsA[4][8192];   // 4 ring slots x [256 rows][32 k] bf16 (64 KiB)
    __shared__ u16 ldsB[4][8192];   // 64 KiB
    const int t = threadIdx.x, l = t & 63, w = t >> 6;
    const int wr = w >> 2, wc = w & 3;

    const int nwg = gridDim.x;
    const int cpx = nwg >> 3;
    const int bid = blockIdx.x;
    const int swz = (bid & 7) * cpx + (bid >> 3);
    const int tm = swz / ntn, tn = swz % ntn;

    f32x4 acc[8][4];
    const f32x4 zero = {0.f, 0.f, 0.f, 0.f};
#pragma unroll
    for (int mi = 0; mi < 8; mi++)
#pragma unroll
        for (int ni = 0; ni < 4; ni++) acc[mi][ni] = zero;

    const int srow = w * 16 + (l >> 2);
    const int kel  = ((l & 3) ^ ((l >> 3) & 3)) * 8;
    const u16* gA0 = A  + (size_t)(tm * 256 + srow) * Kd + kel;
    const u16* gA1 = gA0 + (size_t)128 * Kd;
    const u16* gB0 = Bm + (size_t)(tn * 256 + srow) * Kd + kel;
    const u16* gB1 = gB0 + (size_t)128 * Kd;
    const int ldst = w * 512;

    const int arow = wr * 128 + (l & 15);
    const int brow = wc * 64 + (l & 15);
    const int koff = (((l >> 4) ^ ((l >> 1) & 3)) << 3);

    const int nK = Kd >> 5;

    {
        gload16(gA0, &ldsA[0][ldst]);           gload16(gA1, &ldsA[0][4096 + ldst]);
        gload16(gB0, &ldsB[0][ldst]);           gload16(gB1, &ldsB[0][4096 + ldst]);
        __builtin_amdgcn_sched_barrier(0);
        gload16(gA0 + 32, &ldsA[1][ldst]);      gload16(gA1 + 32, &ldsA[1][4096 + ldst]);
        gload16(gB0 + 32, &ldsB[1][ldst]);      gload16(gB1 + 32, &ldsB[1][4096 + ldst]);
        __builtin_amdgcn_sched_barrier(0);
        gload16(gA0 + 64, &ldsA[2][ldst]);      gload16(gA1 + 64, &ldsA[2][4096 + ldst]);
        gload16(gB0 + 64, &ldsB[2][ldst]);      gload16(gB1 + 64, &ldsB[2][4096 + ldst]);
    }
    asm volatile("s_waitcnt vmcnt(8)" ::: "memory");
    __builtin_amdgcn_s_barrier();

    for (int kt = 0; kt < nK; ++kt) {
        const int sk = kt & 3;
        const bool st = (kt + 3) < nK;
        const int ss = (kt + 3) & 3;
        const int ko = (kt + 3) * 32;

        short8 af[8];
#pragma unroll
        for (int mi = 0; mi < 8; mi++)
            af[mi] = *(const short8*)&ldsA[sk][(arow + mi * 16) * 32 + koff];
        short8 b0 = *(const short8*)&ldsB[sk][(brow + 0) * 32 + koff];
        short8 b1 = *(const short8*)&ldsB[sk][(brow + 16) * 32 + koff];
        if (st) {
            gload16(gA0 + ko, &ldsA[ss][ldst]);
            gload16(gA1 + ko, &ldsA[ss][4096 + ldst]);
        }
        __builtin_amdgcn_s_setprio(1);
#pragma unroll
        for (int mi = 0; mi < 8; mi++)
            acc[mi][0] = __builtin_amdgcn_mfma_f32_16x16x32_bf16(af[mi], b0, acc[mi][0], 0, 0, 0);
#pragma unroll
        for (int mi = 0; mi < 8; mi++)
            acc[mi][1] = __builtin_amdgcn_mfma_f32_16x16x32_bf16(af[mi], b1, acc[mi][1], 0, 0, 0);
        __builtin_amdgcn_s_setprio(0);

        short8 b2 = *(const short8*)&ldsB[sk][(brow + 32) * 32 + koff];
        short8 b3 = *(const short8*)&ldsB[sk][(brow + 48) * 32 + koff];
        if (st) {
            gload16(gB0 + ko, &ldsB[ss][ldst]);
            gload16(gB1 + ko, &ldsB[ss][4096 + ldst]);
        }
        __builtin_amdgcn_s_setprio(1);
#pragma unroll
        for (int mi = 0; mi < 8; mi++)
            acc[mi][2] = __builtin_amdgcn_mfma_f32_16x16x32_bf16(af[mi], b2, acc[mi][2], 0, 0, 0);
#pragma unroll
        for (int mi = 0; mi < 8; mi++)
            acc[mi][3] = __builtin_amdgcn_mfma_f32_16x16x32_bf16(af[mi], b3, acc[mi][3], 0, 0, 0);
        __builtin_amdgcn_s_setprio(0);

        if (kt < nK - 1) {
            if (kt <= nK - 4)      asm volatile("s_waitcnt vmcnt(8)" ::: "memory");
            else if (kt == nK - 3) asm volatile("s_waitcnt vmcnt(4)" ::: "memory");
            else                   asm volatile("s_waitcnt vmcnt(0)" ::: "memory");
            __builtin_amdgcn_s_barrier();
        }
    }

    const int cr = (l >> 4) * 4;
    const int cc = l & 15;
#pragma unroll
    for (int ni = 0; ni < 4; ni++) {
        const int col = tn * 256 + wc * 64 + ni * 16 + cc;
        const float bv = bias[col];
#pragma unroll
        for (int mi = 0; mi < 8; mi++) {
            const int row0 = tm * 256 + wr * 128 + mi * 16 + cr;
#pragma unroll
            for (int q = 0; q < 4; q++) {
                float v = acc[mi][ni][q] + bv;
                if (OUT_F32) ((float*)Cout)[(size_t)(row0 + q) * Ncols + col] = v;
                else         ((u16*)Cout)[(size_t)(row0 + q) * Ncols + col] = f2bf(v);
            }
        }
    }
}

// ---------------------------------------------------------------- fused slice pass v2
// Phase 1: S' = wtq @ xk^T via MFMA (swapped operands: lane-group softmax over m).
// Phase 2: scalar P@V accumulation (float2), xv staged via global_load_lds.
__global__ __launch_bounds__(256) void slice_pass(
        const u16* __restrict__ kv, const float* __restrict__ wtq,
        float* __restrict__ sw_out, float* __restrict__ pst, float* __restrict__ pnorm) {
    __shared__ u16 xk_lds[128 * 128];   // 32 KB: xk half-tile (swizzled), reused for xv (linear)
    __shared__ u16 wtq_lds[MM * DD];    // 8 KB, swizzled chunks
    __shared__ u16 w_lds[MM * 258];     // 16.5 KB (pitch 258: conflict-free column reads)
    const int t = threadIdx.x, l = t & 63, w = t >> 6;
    const int bh = blockIdx.y, b = bh >> 3, h = bh & 7;
    const int n0 = blockIdx.x * 256;

    // stage wtq (f32 -> bf16), chunk-swizzled: phys_chunk = (d>>3) ^ (m&7)
    for (int i = t; i < MM * DD; i += 256) {
        int m = i >> 7, d = i & 127;
        int idx = m * 128 + (((d >> 3) ^ (m & 7)) << 3) + (d & 7);
        wtq_lds[idx] = f2bf(wtq[(size_t)h * MM * DD + i]);
    }

    // staging constants: round j covers rows j*16 + (t>>4), 16B slot (t&15)
    const int srow = t >> 4;
    const int sswz = (t & 15) ^ (srow & 7);     // pre-swizzled source chunk for xk
    const int mrow = l & 15;
    const int kg = l >> 4;                       // 0..3

    // ---------------- phase 1: per half, MFMA scores + softmax over m
    for (int half = 0; half < 2; half++) {
        __syncthreads();    // wtq staged (h=0) / previous half's frag reads done (h=1)
        {
            const u16* src = kv + ((size_t)(b * NN) + n0 + half * 128 + srow) * K2HD + h * DD + sswz * 8;
            for (int j = 0; j < 8; j++)
                gload16(src + (size_t)j * 16 * K2HD, xk_lds + j * 2048 + w * 512);
        }
        __syncthreads();    // xk half staged (vmcnt drained by syncthreads)

        f32x4 s[2][2];
        const f32x4 zero = {0.f, 0.f, 0.f, 0.f};
        s[0][0] = zero; s[0][1] = zero; s[1][0] = zero; s[1][1] = zero;
#pragma unroll
        for (int ks = 0; ks < 4; ks++) {
            const int pc = (((ks << 2) + kg) ^ (l & 7)) << 3;   // swizzled byte-chunk -> elem offset
            short8 a0 = *(const short8*)&wtq_lds[mrow * 128 + pc];
            short8 a1 = *(const short8*)&wtq_lds[(16 + mrow) * 128 + pc];
            short8 bb0 = *(const short8*)&xk_lds[(w * 32 + mrow) * 128 + pc];
            short8 bb1 = *(const short8*)&xk_lds[(w * 32 + 16 + mrow) * 128 + pc];
            s[0][0] = __builtin_amdgcn_mfma_f32_16x16x32_bf16(a0, bb0, s[0][0], 0, 0, 0);
            s[0][1] = __builtin_amdgcn_mfma_f32_16x16x32_bf16(a0, bb1, s[0][1], 0, 0, 0);
            s[1][0] = __builtin_amdgcn_mfma_f32_16x16x32_bf16(a1, bb0, s[1][0], 0, 0, 0);
            s[1][1] = __builtin_amdgcn_mfma_f32_16x16x32_bf16(a1, bb1, s[1][1], 0, 0, 0);
        }

        // softmax over m (32 values live in 4-lane group {l, l^16, l^32, l^48})
#pragma unroll
        for (int nj = 0; nj < 2; nj++) {
            float mx = s[0][nj][0];
#pragma unroll
            for (int mi = 0; mi < 2; mi++)
#pragma unroll
                for (int q = 0; q < 4; q++) mx = fmaxf(mx, s[mi][nj][q]);
            mx = fmaxf(mx, __shfl_xor(mx, 16));
            mx = fmaxf(mx, __shfl_xor(mx, 32));
            float ex[2][4], sum = 0.f;
#pragma unroll
            for (int mi = 0; mi < 2; mi++)
#pragma unroll
                for (int q = 0; q < 4; q++) { ex[mi][q] = __expf(s[mi][nj][q] - mx); sum += ex[mi][q]; }
            sum += __shfl_xor(sum, 16);
            sum += __shfl_xor(sum, 32);
            const float inv = 1.f / sum;
            const int ncol = half * 128 + w * 32 + nj * 16 + mrow;
#pragma unroll
            for (int mi = 0; mi < 2; mi++)
#pragma unroll
                for (int q = 0; q < 4; q++) {
                    const int m = mi * 16 + kg * 4 + q;
                    const float wv = ex[mi][q] * inv;
                    sw_out[((size_t)bh * MM + m) * NN + n0 + ncol] = wv;
                    w_lds[m * 258 + ncol] = f2bf(wv);
                }
        }
    }

    // ---------------- phase 2: partial slice_token. thread -> (m = t>>3, d-range (t&7)*16)
    const int am = t >> 3;
    const int ad = (t & 7) * 16;
    float2 accv[8];
#pragma unroll
    for (int j = 0; j < 8; j++) accv[j] = make_float2(0.f, 0.f);
    float wsum = 0.f;

    for (int half = 0; half < 2; half++) {
        __syncthreads();    // phase-1 xk reads + w_lds writes done (h=0) / xv reads done (h=1)
        {
            const u16* src = kv + ((size_t)(b * NN) + n0 + half * 128 + srow) * K2HD + HDIM + h * DD + (t & 15) * 8;
            for (int j = 0; j < 8; j++)
                gload16(src + (size_t)j * 16 * K2HD, xk_lds + j * 2048 + w * 512);
        }
        __syncthreads();
        for (int n = 0; n < 128; n++) {
            float wv = bf2f(w_lds[am * 258 + half * 128 + n]);
            wsum += wv;
            const u32* xvr = (const u32*)&xk_lds[n * 128 + ad];
#pragma unroll
            for (int j = 0; j < 8; j++) {
                u32 xd = xvr[j];
                accv[j].x += wv * bflo(xd);
                accv[j].y += wv * bfhi(xd);
            }
        }
    }

    float* dst = &pst[(((size_t)bh * 64 + blockIdx.x) * MM + am) * DD + ad];
#pragma unroll
    for (int j = 0; j < 8; j += 2) {
        float4 v = make_float4(accv[j].x, accv[j].y, accv[j + 1].x, accv[j + 1].y);
        *(float4*)&dst[j * 2] = v;
    }
    if ((t & 7) == 0) pnorm[((size_t)bh * 64 + blockIdx.x) * MM + am] = wsum;
}

// ---------------------------------------------------------------- reduce pst partials (parallel)
// grid (8, 32): block (es, bh). st_red[bh][e] = (sum_g pst[bh][g][e]) / (norm[e>>7]+1e-5) as bf16
__global__ __launch_bounds__(256) void reduce_pst(const float* __restrict__ pst,
                                                  const float* __restrict__ pnorm,
                                                  u16* __restrict__ st_red) {
    __shared__ float norm_lds[MM];
    const int bh = blockIdx.y, es = blockIdx.x, t = threadIdx.x;
    if (t < MM) {
        float s = 0.f;
        for (int g = 0; g < 64; g++) s += pnorm[((size_t)bh * 64 + g) * MM + t];
        norm_lds[t] = s + 1e-5f;
    }
    __syncthreads();
    const int e = es * 512 + t * 2;
    float ax = 0.f, ay = 0.f;
    for (int g = 0; g < 64; g++) {
        const float2 v = *(const float2*)&pst[((size_t)bh * 64 + g) * 4096 + e];
        ax += v.x; ay += v.y;
    }
    const float nv = norm_lds[e >> 7];
    u32 pk = (u32)f2bf(ax / nv) | ((u32)f2bf(ay / nv) << 16);
    ((u32*)st_red)[((size_t)bh * 4096 + e) >> 1] = pk;
}

// ---------------------------------------------------------------- finalize (per b,h)
__global__ void finalize_kernel(const u16* __restrict__ st_red,
                                const float* __restrict__ qkvp, float* __restrict__ attn_out,
                                float* __restrict__ otw) {
    __shared__ float qt[MM * 384];      // 48 KB
    __shared__ u16 st_lds[MM * DD];     // 8 KB
    __shared__ float dots[MM * MM];     // 4 KB
    const int bh = blockIdx.x, h = bh & 7, t = threadIdx.x;

    {
        const uint4* src = (const uint4*)(st_red + (size_t)bh * 4096);
        ((uint4*)st_lds)[t] = src[t];
        ((uint4*)st_lds)[t + 256] = src[t + 256];
    }
    __syncthreads();
    const float* qw = qkvp + (size_t)h * DD * 384;
    for (int i = 0; i < 48; i++) {
        int j = t + i * 256;
        int m = j / 384, e = j - m * 384;
        float s = 0.f;
        for (int d = 0; d < DD; d++) s += bf2f(st_lds[m * DD + d]) * qw[d * 384 + e];
        qt[m * 384 + e] = s;
    }
    __syncthreads();
    const float scale = 0.08838834764831845f;
#pragma unroll
    for (int i = 0; i < 4; i++) {
        int idx = t * 4 + i;
        int qi = idx >> 5, kj = idx & 31;
        float s = 0.f;
        for (int d = 0; d < DD; d++) s += qt[qi * 384 + d] * qt[kj * 384 + 128 + d];
        dots[idx] = s * scale;
    }
    __syncthreads();
    if (t < MM) {
        float mx = -1e30f;
        float ex[MM];
#pragma unroll
        for (int j = 0; j < MM; j++) mx = fmaxf(mx, dots[t * MM + j]);
        float sm = 0.f;
#pragma unroll
        for (int j = 0; j < MM; j++) { ex[j] = __expf(dots[t * MM + j] - mx); sm += ex[j]; }
        float inv = 1.f / sm;
#pragma unroll
        for (int j = 0; j < MM; j++) {
            float v = ex[j] * inv;
            dots[t * MM + j] = v;
            attn_out[((size_t)bh * MM + t) * MM + j] = v;
        }
    }
    __syncthreads();
#pragma unroll
    for (int i = 0; i < 16; i++) {
        int e = t + i * 256;
        int m = e >> 7, d = e & 127;
        float s = 0.f;
#pragma unroll
        for (int j = 0; j < MM; j++) s += dots[m * MM + j] * qt[j * 384 + 256 + d];
        otw[(size_t)bh * 4096 + e] = s;
    }
}

// ---------------------------------------------------------------- scatter y[n, h*128+d] = sum_m ot[m,d]*w[m,n]
__global__ void scatter_kernel(const float* __restrict__ otw, const float* __restrict__ sw,
                               u16* __restrict__ y) {
    __shared__ float ot_lds[MM * 132];  // phys: m*132 + (d>>5)*33 + (d&31)
    __shared__ float w_lds[MM * 64];
    const int bh = blockIdx.y, b = bh >> 3, h = bh & 7, t = threadIdx.x;
    const int n0 = blockIdx.x * 64;

    for (int i = t; i < MM * DD; i += 256) {
        int m = i >> 7, d = i & 127;
        ot_lds[m * 132 + (d >> 5) * 33 + (d & 31)] = otw[(size_t)bh * 4096 + i];
    }
    for (int i = t; i < MM * 64; i += 256) {
        int m = i >> 6, nl = i & 63;
        w_lds[i] = sw[((size_t)bh * MM + m) * NN + n0 + nl];
    }
    __syncthreads();

    const int nl = t >> 2, dq = t & 3;
    float acc[32];
#pragma unroll
    for (int j = 0; j < 32; j++) acc[j] = 0.f;
    for (int m = 0; m < MM; m++) {
        float wv = w_lds[m * 64 + nl];
        const float* otr = &ot_lds[m * 132 + dq * 33];
#pragma unroll
        for (int j = 0; j < 32; j++) acc[j] += wv * otr[j];
    }
    u16* dstp = y + (size_t)(b * NN + n0 + nl) * HDIM + h * DD + dq * 32;
#pragma unroll
    for (int j = 0; j < 16; j++) {
        u32 pk = (u32)f2bf(acc[2 * j]) | ((u32)f2bf(acc[2 * j + 1]) << 16);
        ((u32*)dstp)[j] = pk;
    }
}

// ---------------------------------------------------------------- launch
extern "C" void kernel_launch(void* const* d_in, const int* in_sizes, int n_in,
                              void* d_out, int out_size, void* d_ws, size_t ws_size,
                              hipStream_t stream) {
    const float* x        = (const float*)d_in[0];
    const float* wkv      = (const float*)d_in[1];
    const float* bkv      = (const float*)d_in[2];
    const float* wtq      = (const float*)d_in[3];
    const float* wtq_bias = (const float*)d_in[4];
    const float* qkvp     = (const float*)d_in[5];
    const float* outw     = (const float*)d_in[6];
    const float* outb     = (const float*)d_in[7];

    float* out  = (float*)d_out;
    float* out0 = out;                      // [B,N,HD]           67108864
    float* out1 = out + 67108864;           // slice_weights      16777216
    float* out2 = out + 83886080;           // temperature + bias
    float* out4 = out + 83886337;           // attn_weights       32768

    char* ws = (char*)d_ws;
    u16*   xb    = (u16*)(ws);                          // 134217728 B (reused as y after GEMM1)
    u16*   kvb   = (u16*)(ws + 134217728);              // 268435456 B
    u16*   st_red= (u16*)(ws + 134217728);              // aliases kvb (kv dead after slice_pass)
    u16*   wkvb  = (u16*)(ws + 402653184);              // 4194304 B
    u16*   outwb = (u16*)(ws + 406847488);              // 2097152 B
    float* pst   = (float*)(ws + 408944640);            // 33554432 B
    float* pnorm = (float*)(ws + 442499072);            // 262144 B
    float* otws  = (float*)(ws + 442761216);            // 524288 B

    convert_kernel<<<dim3(2048), dim3(256), 0, stream>>>(x, wkv, outw, xb, wkvb, outwb, wtq_bias, out2);
    gemm256<0><<<dim3(256 * 8), dim3(512), 0, stream>>>(xb, wkvb, bkv, (void*)kvb, K2HD, HDIM, 8);
    slice_pass<<<dim3(64, 32), dim3(256), 0, stream>>>(kvb, wtq, out1, pst, pnorm);
    reduce_pst<<<dim3(8, 32), dim3(256), 0, stream>>>(pst, pnorm, st_red);
    finalize_kernel<<<dim3(32), dim3(256), 0, stream>>>(st_red, qkvp, out4, otws);
    scatter_kernel<<<dim3(256, 32), dim3(256), 0, stream>>>(otws, out1, xb);
    gemm256<1><<<dim3(256 * 4), dim3(512), 0, stream>>>(xb, outwb, outb, (void*)out0, HDIM, HDIM, 4);
}